// Round 11
// baseline (186.513 us; speedup 1.0000x reference)
//
#include <hip/hip_runtime.h>
#include <hip/hip_bf16.h>
#include <math.h>

#define N_NODES 100000
#define E_EDGES 1600000
#define F_IN    256
#define HD      128     // H*D
#define NHEAD   4
#define DHEAD   32
#define NEG_SLOPE 0.2f
#define CAP     64      // per-dst bucket capacity; == wave size
#define NBIN    200
#define BINW    500     // dsts per bin
#define CHUNK   8192
#define NCHUNK  196     // ceil(1.6M / 8192)
#define BINCAP  16384   // slots per bin (mean 8000)
#define NC      144     // gemm cols: 128 h + 4 el + 4 er + 8 pad
#define NCT     9       // col tiles of 16
#define GEMS1   196     // gemm blocks in fat1 (rows 0..50175, 256 rows/block)
#define GEMS2   195     // gemm blocks in fat2 (rows 50176..100095)

typedef __attribute__((ext_vector_type(8))) __bf16 bf16x8;
typedef __attribute__((ext_vector_type(4))) float  f32x4;
typedef __attribute__((ext_vector_type(8))) unsigned short u16x8;

__device__ __forceinline__ unsigned short f2bf(float x) {
    unsigned int b = __float_as_uint(x);
    b += 0x7fffu + ((b >> 16) & 1u);       // round-to-nearest-even
    return (unsigned short)(b >> 16);
}
__device__ __forceinline__ float bf2f(unsigned short u) {
    return __uint_as_float((unsigned int)u << 16);
}

// ---------------- K0: build 144-col bf16 weight buffer, pre-swizzled ----------------
__global__ void k_prep(const float* __restrict__ W, const float* __restrict__ al,
                       const float* __restrict__ ar, unsigned short* __restrict__ wbf,
                       int* __restrict__ cursor) {
    if (blockIdx.x == 0) {
        for (int i = threadIdx.x; i < NBIN; i += NC) cursor[i] = 0;
    }
    const int k = blockIdx.x;       // 0..255
    const int c = threadIdx.x;      // 0..143
    float v;
    if (c < 128) {
        v = W[k * HD + c];
    } else if (c < 132) {
        int h = c - 128; float s = 0.f;
        for (int d = 0; d < DHEAD; d++) s += W[k * HD + h * DHEAD + d] * al[h * DHEAD + d];
        v = s;
    } else if (c < 136) {
        int h = c - 132; float s = 0.f;
        for (int d = 0; d < DHEAD; d++) s += W[k * HD + h * DHEAD + d] * ar[h * DHEAD + d];
        v = s;
    } else {
        v = 0.f;
    }
    *(unsigned short*)((char*)wbf + (size_t)c * 512 + ((2 * k) ^ ((c & 7) << 4))) = f2bf(v);
}

// ---------------- shared gemm role: 512 thr, 256 rows/block, 144 cols ----------
// NT loads on X (perm bijective -> read-once), NT stores on hb/el/er (consumed
// kernels later) -> keep L2 for wbf + co-resident bin-role traffic.
__device__ __forceinline__ void gemm_role(int bid, int tid,
        unsigned char* smem, const float* __restrict__ X,
        const unsigned short* __restrict__ wbf, const int* __restrict__ perm,
        unsigned short* __restrict__ hb, float* __restrict__ el,
        float* __restrict__ er) {
    unsigned short* Bs = (unsigned short*)smem;   // NC*512 = 73728 B swizzled W'
    {   // linear stage (16B chunks): 4608 float4 / 512 thr = 9 each
        const float4* srcv = (const float4*)wbf;
        float4* dstv = (float4*)Bs;
#pragma unroll
        for (int i = 0; i < 9; i++) dstv[tid + i * 512] = srcv[tid + i * 512];
    }
    __syncthreads();

    const int l   = tid & 63;
    const int wv  = tid >> 6;           // 0..7
    const int l15 = l & 15;
    const int kg  = l >> 4;
    const int rowbase = bid * 256 + wv * 32;

    int r0 = rowbase + l15;      if (r0 >= N_NODES) r0 = N_NODES - 1;
    int r1 = rowbase + 16 + l15; if (r1 >= N_NODES) r1 = N_NODES - 1;
    const f32x4* aptr0 = (const f32x4*)(X + (long)perm[r0] * F_IN + kg * 8);
    const f32x4* aptr1 = (const f32x4*)(X + (long)perm[r1] * F_IN + kg * 8);

    f32x4 acc[2][NCT];
#pragma unroll
    for (int rt = 0; rt < 2; rt++)
#pragma unroll
        for (int ct = 0; ct < NCT; ct++) acc[rt][ct] = (f32x4){0.f, 0.f, 0.f, 0.f};

#pragma unroll
    for (int k0 = 0; k0 < F_IN; k0 += 32) {
        bf16x8 a0, a1;
        {
            f32x4 v0 = __builtin_nontemporal_load(aptr0 + (k0 >> 2));
            f32x4 v1 = __builtin_nontemporal_load(aptr0 + (k0 >> 2) + 1);
            a0[0]=(__bf16)v0[0]; a0[1]=(__bf16)v0[1]; a0[2]=(__bf16)v0[2]; a0[3]=(__bf16)v0[3];
            a0[4]=(__bf16)v1[0]; a0[5]=(__bf16)v1[1]; a0[6]=(__bf16)v1[2]; a0[7]=(__bf16)v1[3];
        }
        {
            f32x4 v0 = __builtin_nontemporal_load(aptr1 + (k0 >> 2));
            f32x4 v1 = __builtin_nontemporal_load(aptr1 + (k0 >> 2) + 1);
            a1[0]=(__bf16)v0[0]; a1[1]=(__bf16)v0[1]; a1[2]=(__bf16)v0[2]; a1[3]=(__bf16)v0[3];
            a1[4]=(__bf16)v1[0]; a1[5]=(__bf16)v1[1]; a1[6]=(__bf16)v1[2]; a1[7]=(__bf16)v1[3];
        }
        const int sb = k0 * 2 + kg * 16;
#pragma unroll
        for (int ct = 0; ct < NCT; ct++) {
            int c = ct * 16 + l15;
            bf16x8 b = *(const bf16x8*)((const char*)Bs + c * 512 + (sb ^ ((c & 7) << 4)));
            acc[0][ct] = __builtin_amdgcn_mfma_f32_16x16x32_bf16(a0, b, acc[0][ct], 0, 0, 0);
            acc[1][ct] = __builtin_amdgcn_mfma_f32_16x16x32_bf16(a1, b, acc[1][ct], 0, 0, 0);
        }
    }

    // C/D layout: col = l&15, row = (l>>4)*4 + reg (m89-verified)
#pragma unroll
    for (int rt = 0; rt < 2; rt++)
#pragma unroll
        for (int i = 0; i < 4; i++) {
            int row = rowbase + rt * 16 + kg * 4 + i;
            if (row < N_NODES) {
                unsigned short* op = hb + (long)row * HD + l15;
#pragma unroll
                for (int ct = 0; ct < 8; ct++)
                    __builtin_nontemporal_store(f2bf(acc[rt][ct][i]), op + ct * 16);
                float v = acc[rt][8][i];
                if (l15 < 4)      __builtin_nontemporal_store(v, el + (long)row * 4 + l15);
                else if (l15 < 8) __builtin_nontemporal_store(v, er + (long)row * 4 + (l15 - 4));
            }
        }
}

// ---------------- FAT1: binA (blocks 0..195)  ||  gemm rows [0, 50176) ----------
__global__ __launch_bounds__(512, 4) void k_fat1(const float* __restrict__ X,
        const unsigned short* __restrict__ wbf, const int* __restrict__ perm,
        unsigned short* __restrict__ hb, float* __restrict__ el, float* __restrict__ er,
        const int* __restrict__ src, const int* __restrict__ dst,
        int* __restrict__ cursor, unsigned int* __restrict__ binbuf) {
    __shared__ __align__(16) unsigned char smem[73728];
    const int tid = threadIdx.x;

    if (blockIdx.x < NCHUNK) {
        // ---------------- binA role ----------------
        unsigned int*  buf     = (unsigned int*)smem;             // 32768 B
        unsigned char* binid   = smem + 32768;                    //  8192 B
        unsigned int*  hist    = (unsigned int*)(smem + 40960);
        unsigned int*  pfx     = (unsigned int*)(smem + 41792);
        unsigned int*  base_sh = (unsigned int*)(smem + 42624);
        unsigned int*  cnt2    = (unsigned int*)(smem + 43456);
        const int e0 = blockIdx.x * CHUNK;
        const int n = min(CHUNK, E_EDGES - e0);

        for (int i = tid; i < NBIN; i += 512) { hist[i] = 0; cnt2[i] = 0; }
        __syncthreads();
        for (int i = tid; i < n; i += 512) {
            int d = __builtin_nontemporal_load(dst + e0 + i);
            atomicAdd(&hist[d / BINW], 1u);
        }
        __syncthreads();
        if (tid < NBIN) pfx[tid] = hist[tid];
        __syncthreads();
        for (int off = 1; off < NBIN; off <<= 1) {     // inclusive scan
            unsigned v = (tid < NBIN) ? pfx[tid] : 0;
            unsigned u = (tid >= off && tid < NBIN) ? pfx[tid - off] : 0;
            __syncthreads();
            if (tid < NBIN) pfx[tid] = v + u;
            __syncthreads();
        }
        if (tid < NBIN) base_sh[tid] = (unsigned)atomicAdd(cursor + tid, (int)hist[tid]);
        __syncthreads();
        for (int i = tid; i < n; i += 512) {
            int d = __builtin_nontemporal_load(dst + e0 + i);
            int s = __builtin_nontemporal_load(src + e0 + i);
            int b = d / BINW;
            unsigned pos = atomicAdd(&cnt2[b], 1u);
            unsigned idx = pfx[b] - hist[b] + pos;
            buf[idx] = ((unsigned)(d - b * BINW) << 17) | (unsigned)s;
            binid[idx] = (unsigned char)b;
        }
        __syncthreads();
        for (int i = tid; i < n; i += 512) {
            int b = binid[i];
            unsigned ex = pfx[b] - hist[b];
            unsigned gpos = base_sh[b] + ((unsigned)i - ex);
            if (gpos < BINCAP)
                __builtin_nontemporal_store(buf[i], binbuf + (long)b * BINCAP + gpos);
        }
    } else {
        gemm_role(blockIdx.x - NCHUNK, tid, smem, X, wbf, perm, hb, el, er);
    }
}

// ---------------- FAT2: binB (blocks 0..199)  ||  gemm rows [50176, 100096) --------
__global__ __launch_bounds__(512, 4) void k_fat2(const unsigned int* __restrict__ binbuf,
        const int* __restrict__ cursor, int* __restrict__ cnt, int* __restrict__ bucket,
        const float* __restrict__ X, const unsigned short* __restrict__ wbf,
        const int* __restrict__ perm, unsigned short* __restrict__ hb,
        float* __restrict__ el, float* __restrict__ er) {
    __shared__ __align__(16) unsigned char smem[73728];
    if (blockIdx.x < NBIN) {
        int* cnt_l = (int*)smem;                      // 2000 B
        const int b = blockIdx.x;
        const int n = min(cursor[b], BINCAP);
        for (int i = threadIdx.x; i < BINW; i += 512) cnt_l[i] = 0;
        __syncthreads();
        const unsigned int* bp = binbuf + (long)b * BINCAP;
        for (int i = threadIdx.x; i < n; i += 512) {
            unsigned p = __builtin_nontemporal_load(bp + i);
            int dl = (int)(p >> 17);
            int s  = (int)(p & 0x1FFFFu);
            int pos = atomicAdd(&cnt_l[dl], 1);
            if (pos < CAP)
                __builtin_nontemporal_store(s, bucket + ((long)b * BINW + dl) * CAP + pos);
        }
        __syncthreads();
        for (int i = threadIdx.x; i < BINW; i += 512) cnt[b * BINW + i] = cnt_l[i];
    } else {
        gemm_role(GEMS1 + (blockIdx.x - NBIN), threadIdx.x, smem, X, wbf, perm,
                  hb, el, er);
    }
}

// ---------------- K4: aggregation (4 edge slots in flight), softmax, ELU ----------
// lane = g*16 + l4: g = edge slot (0..3), l4 = col chunk (8 cols, 16 B).
// NT on bucket load + out store; hb/el keep normal caching (the reuse set).
__global__ __launch_bounds__(256) void k_aggr(const float* __restrict__ el,
        const float* __restrict__ er, const int* __restrict__ cnt,
        const int* __restrict__ bucket, const unsigned short* __restrict__ hb,
        float* __restrict__ out) {
    int wid = (int)((blockIdx.x * (long)blockDim.x + threadIdx.x) >> 6);
    if (wid >= N_NODES) return;
    const int lane = threadIdx.x & 63;
    const int g    = lane >> 4;
    const int l4   = lane & 15;
    const int head = l4 >> 2;
    int deg = cnt[wid];
    if (deg > CAP) deg = CAP;
    const float ern = er[(long)wid * 4 + head];
    int myS = (lane < deg) ? __builtin_nontemporal_load(bucket + (long)wid * CAP + lane) : 0;
    float acc[8];
#pragma unroll
    for (int j = 0; j < 8; j++) acc[j] = 0.f;
    float asum = 0.f;
    for (int i = 0; i < deg; i += 4) {
        int e = i + g;
        int s = __shfl(myS, e & 63, 64);
        u16x8 hv = *(const u16x8*)(hb + (long)s * HD + l4 * 8);
        float a = 0.f;
        if (e < deg) {
            float v = el[(long)s * 4 + head] + ern;
            v = v > 0.f ? v : NEG_SLOPE * v;
            a = __expf(v);
        }
        asum += a;
#pragma unroll
        for (int j = 0; j < 8; j++) acc[j] += bf2f(hv[j]) * a;
    }
#pragma unroll
    for (int off = 16; off <= 32; off <<= 1) {
        asum += __shfl_xor(asum, off, 64);
#pragma unroll
        for (int j = 0; j < 8; j++) acc[j] += __shfl_xor(acc[j], off, 64);
    }
    if (g == 0) {
        float inv = asum > 0.f ? 1.f / asum : 0.f;
        f32x4 o0, o1;
        float t;
        t = acc[0] * inv; o0[0] = t > 0.f ? t : __expf(t) - 1.f;
        t = acc[1] * inv; o0[1] = t > 0.f ? t : __expf(t) - 1.f;
        t = acc[2] * inv; o0[2] = t > 0.f ? t : __expf(t) - 1.f;
        t = acc[3] * inv; o0[3] = t > 0.f ? t : __expf(t) - 1.f;
        t = acc[4] * inv; o1[0] = t > 0.f ? t : __expf(t) - 1.f;
        t = acc[5] * inv; o1[1] = t > 0.f ? t : __expf(t) - 1.f;
        t = acc[6] * inv; o1[2] = t > 0.f ? t : __expf(t) - 1.f;
        t = acc[7] * inv; o1[3] = t > 0.f ? t : __expf(t) - 1.f;
        f32x4* op = (f32x4*)(out + (long)wid * HD + l4 * 8);
        __builtin_nontemporal_store(o0, op);
        __builtin_nontemporal_store(o1, op + 1);
    }
}

// ---------------- launch ----------------
extern "C" void kernel_launch(void* const* d_in, const int* in_sizes, int n_in,
                              void* d_out, int out_size, void* d_ws, size_t ws_size,
                              hipStream_t stream) {
    const float* features = (const float*)d_in[0];
    const float* W        = (const float*)d_in[1];
    const float* attn_l   = (const float*)d_in[2];
    const float* attn_r   = (const float*)d_in[3];
    const int*   src      = (const int*)d_in[4];
    const int*   dst      = (const int*)d_in[5];
    const int*   perm     = (const int*)d_in[6];
    float* out = (float*)d_out;

    char* ws = (char*)d_ws;
    const size_t OFF_HB   = 0;                 // N*128 bf16 = 25,600,000 B
    const size_t OFF_EL   = 25600000;          // N*4 f32
    const size_t OFF_ER   = 27200000;
    const size_t OFF_CNT  = 28800000;          // N int
    const size_t OFF_CUR  = 29200000;          // NBIN ints (4 KB reserved)
    const size_t OFF_WBF  = 29204096;          // 144*512 = 73,728 B (reserve 81,920)
    const size_t OFF_BKT  = 29286016;          // N*CAP int = 25,600,000 B
    const size_t OFF_BINB = 54886016;          // NBIN*BINCAP u32 = 13,107,200 B
    // end ~68.0 MB

    unsigned short* hb    = (unsigned short*)(ws + OFF_HB);
    float* el     = (float*)(ws + OFF_EL);
    float* er     = (float*)(ws + OFF_ER);
    int*   cnt    = (int*)(ws + OFF_CNT);
    int*   cursor = (int*)(ws + OFF_CUR);
    unsigned short* wbf = (unsigned short*)(ws + OFF_WBF);
    int*   bucket = (int*)(ws + OFF_BKT);
    unsigned int* binbuf = (unsigned int*)(ws + OFF_BINB);

    k_prep<<<F_IN, NC, 0, stream>>>(W, attn_l, attn_r, wbf, cursor);
    k_fat1<<<NCHUNK + GEMS1, 512, 0, stream>>>(features, wbf, perm, hb, el, er,
                                               src, dst, cursor, binbuf);
    k_fat2<<<NBIN + GEMS2, 512, 0, stream>>>(binbuf, cursor, cnt, bucket,
                                             features, wbf, perm, hb, el, er);
    k_aggr<<<(N_NODES * 64 + 255) / 256, 256, 0, stream>>>(el, er, cnt, bucket, hb, out);
}

// Round 12
// 139.537 us; speedup vs baseline: 1.3367x; 1.3367x over previous
//
#include <hip/hip_runtime.h>
#include <hip/hip_bf16.h>
#include <math.h>

#define N_NODES 100000
#define E_EDGES 1600000
#define F_IN    256
#define HD      128     // H*D
#define NHEAD   4
#define DHEAD   32
#define NEG_SLOPE 0.2f
#define CAP     64      // per-dst bucket capacity; == wave size
#define NBIN    200
#define BINW    500     // dsts per bin
#define CHUNK   8192
#define NCHUNK  196     // ceil(1.6M / 8192)
#define BINCAP  16384   // slots per bin (mean 8000)
#define NC      144     // gemm cols: 128 h + 4 el + 4 er + 8 pad
#define NCT     9       // col tiles of 16
#define GEMS1   196     // gemm blocks in fat1 (rows 0..50175, 256 rows/block)
#define GEMS2   195     // gemm blocks in fat2 (rows 50176..100095)

typedef __attribute__((ext_vector_type(8))) __bf16 bf16x8;
typedef __attribute__((ext_vector_type(4))) float  f32x4;
typedef __attribute__((ext_vector_type(8))) unsigned short u16x8;

__device__ __forceinline__ unsigned short f2bf(float x) {
    unsigned int b = __float_as_uint(x);
    b += 0x7fffu + ((b >> 16) & 1u);       // round-to-nearest-even
    return (unsigned short)(b >> 16);
}
__device__ __forceinline__ float bf2f(unsigned short u) {
    return __uint_as_float((unsigned int)u << 16);
}

// ---------------- K0: build 144-col bf16 weight buffer, pre-swizzled ----------------
// cols 0..127 = W; col 128+h = W @ attn_l[h]; col 132+h = W @ attn_r[h]; 136.. = 0.
// byte position = c*512 + ((2k) ^ ((c&7)<<4)). Block 0 also zeroes cursor.
__global__ void k_prep(const float* __restrict__ W, const float* __restrict__ al,
                       const float* __restrict__ ar, unsigned short* __restrict__ wbf,
                       int* __restrict__ cursor) {
    if (blockIdx.x == 0) {
        for (int i = threadIdx.x; i < NBIN; i += NC) cursor[i] = 0;
    }
    const int k = blockIdx.x;       // 0..255
    const int c = threadIdx.x;      // 0..143
    float v;
    if (c < 128) {
        v = W[k * HD + c];
    } else if (c < 132) {
        int h = c - 128; float s = 0.f;
        for (int d = 0; d < DHEAD; d++) s += W[k * HD + h * DHEAD + d] * al[h * DHEAD + d];
        v = s;
    } else if (c < 136) {
        int h = c - 132; float s = 0.f;
        for (int d = 0; d < DHEAD; d++) s += W[k * HD + h * DHEAD + d] * ar[h * DHEAD + d];
        v = s;
    } else {
        v = 0.f;
    }
    *(unsigned short*)((char*)wbf + (size_t)c * 512 + ((2 * k) ^ ((c & 7) << 4))) = f2bf(v);
}

// ---------------- shared gemm role: 512 thr, 256 rows/block, 144 cols ----------
__device__ __forceinline__ void gemm_role(int bid, int tid,
        unsigned char* smem, const float* __restrict__ X,
        const unsigned short* __restrict__ wbf, const int* __restrict__ perm,
        unsigned short* __restrict__ hb, float* __restrict__ el,
        float* __restrict__ er) {
    unsigned short* Bs = (unsigned short*)smem;   // NC*512 = 73728 B swizzled W'
    {   // linear stage (16B chunks): 4608 float4 / 512 thr = 9 each
        const float4* srcv = (const float4*)wbf;
        float4* dstv = (float4*)Bs;
#pragma unroll
        for (int i = 0; i < 9; i++) dstv[tid + i * 512] = srcv[tid + i * 512];
    }
    __syncthreads();

    const int l   = tid & 63;
    const int wv  = tid >> 6;           // 0..7
    const int l15 = l & 15;
    const int kg  = l >> 4;
    const int rowbase = bid * 256 + wv * 32;

    int r0 = rowbase + l15;      if (r0 >= N_NODES) r0 = N_NODES - 1;
    int r1 = rowbase + 16 + l15; if (r1 >= N_NODES) r1 = N_NODES - 1;
    const float* aptr0 = X + (long)perm[r0] * F_IN + kg * 8;
    const float* aptr1 = X + (long)perm[r1] * F_IN + kg * 8;

    f32x4 acc[2][NCT];
#pragma unroll
    for (int rt = 0; rt < 2; rt++)
#pragma unroll
        for (int ct = 0; ct < NCT; ct++) acc[rt][ct] = (f32x4){0.f, 0.f, 0.f, 0.f};

#pragma unroll
    for (int k0 = 0; k0 < F_IN; k0 += 32) {
        bf16x8 a0, a1;
        {
            float4 v0 = *(const float4*)(aptr0 + k0);
            float4 v1 = *(const float4*)(aptr0 + k0 + 4);
            a0[0]=(__bf16)v0.x; a0[1]=(__bf16)v0.y; a0[2]=(__bf16)v0.z; a0[3]=(__bf16)v0.w;
            a0[4]=(__bf16)v1.x; a0[5]=(__bf16)v1.y; a0[6]=(__bf16)v1.z; a0[7]=(__bf16)v1.w;
        }
        {
            float4 v0 = *(const float4*)(aptr1 + k0);
            float4 v1 = *(const float4*)(aptr1 + k0 + 4);
            a1[0]=(__bf16)v0.x; a1[1]=(__bf16)v0.y; a1[2]=(__bf16)v0.z; a1[3]=(__bf16)v0.w;
            a1[4]=(__bf16)v1.x; a1[5]=(__bf16)v1.y; a1[6]=(__bf16)v1.z; a1[7]=(__bf16)v1.w;
        }
        const int sb = k0 * 2 + kg * 16;
#pragma unroll
        for (int ct = 0; ct < NCT; ct++) {
            int c = ct * 16 + l15;
            bf16x8 b = *(const bf16x8*)((const char*)Bs + c * 512 + (sb ^ ((c & 7) << 4)));
            acc[0][ct] = __builtin_amdgcn_mfma_f32_16x16x32_bf16(a0, b, acc[0][ct], 0, 0, 0);
            acc[1][ct] = __builtin_amdgcn_mfma_f32_16x16x32_bf16(a1, b, acc[1][ct], 0, 0, 0);
        }
    }

    // C/D layout: col = l&15, row = (l>>4)*4 + reg (m89-verified)
#pragma unroll
    for (int rt = 0; rt < 2; rt++)
#pragma unroll
        for (int i = 0; i < 4; i++) {
            int row = rowbase + rt * 16 + kg * 4 + i;
            if (row < N_NODES) {
                unsigned short* op = hb + (long)row * HD + l15;
#pragma unroll
                for (int ct = 0; ct < 8; ct++) op[ct * 16] = f2bf(acc[rt][ct][i]);
                float v = acc[rt][8][i];
                if (l15 < 4)      el[(long)row * 4 + l15]       = v;
                else if (l15 < 8) er[(long)row * 4 + (l15 - 4)] = v;
            }
        }
}

// ---------------- FAT1: binA (blocks 0..195)  ||  gemm rows [0, 50176) ----------
__global__ __launch_bounds__(512, 4) void k_fat1(const float* __restrict__ X,
        const unsigned short* __restrict__ wbf, const int* __restrict__ perm,
        unsigned short* __restrict__ hb, float* __restrict__ el, float* __restrict__ er,
        const int* __restrict__ src, const int* __restrict__ dst,
        int* __restrict__ cursor, unsigned int* __restrict__ binbuf) {
    __shared__ __align__(16) unsigned char smem[73728];
    const int tid = threadIdx.x;

    if (blockIdx.x < NCHUNK) {
        // ---------------- binA role ----------------
        unsigned int*  buf     = (unsigned int*)smem;             // 32768 B
        unsigned char* binid   = smem + 32768;                    //  8192 B
        unsigned int*  hist    = (unsigned int*)(smem + 40960);
        unsigned int*  pfx     = (unsigned int*)(smem + 41792);
        unsigned int*  base_sh = (unsigned int*)(smem + 42624);
        unsigned int*  cnt2    = (unsigned int*)(smem + 43456);
        const int e0 = blockIdx.x * CHUNK;
        const int n = min(CHUNK, E_EDGES - e0);

        for (int i = tid; i < NBIN; i += 512) { hist[i] = 0; cnt2[i] = 0; }
        __syncthreads();
        for (int i = tid; i < n; i += 512) {
            int d = dst[e0 + i];
            atomicAdd(&hist[d / BINW], 1u);
        }
        __syncthreads();
        if (tid < NBIN) pfx[tid] = hist[tid];
        __syncthreads();
        for (int off = 1; off < NBIN; off <<= 1) {     // inclusive scan
            unsigned v = (tid < NBIN) ? pfx[tid] : 0;
            unsigned u = (tid >= off && tid < NBIN) ? pfx[tid - off] : 0;
            __syncthreads();
            if (tid < NBIN) pfx[tid] = v + u;
            __syncthreads();
        }
        if (tid < NBIN) base_sh[tid] = (unsigned)atomicAdd(cursor + tid, (int)hist[tid]);
        __syncthreads();
        for (int i = tid; i < n; i += 512) {
            int d = dst[e0 + i];
            int s = src[e0 + i];
            int b = d / BINW;
            unsigned pos = atomicAdd(&cnt2[b], 1u);
            unsigned idx = pfx[b] - hist[b] + pos;
            buf[idx] = ((unsigned)(d - b * BINW) << 17) | (unsigned)s;
            binid[idx] = (unsigned char)b;
        }
        __syncthreads();
        for (int i = tid; i < n; i += 512) {
            int b = binid[i];
            unsigned ex = pfx[b] - hist[b];
            unsigned gpos = base_sh[b] + ((unsigned)i - ex);
            if (gpos < BINCAP) binbuf[(long)b * BINCAP + gpos] = buf[i];
        }
    } else {
        gemm_role(blockIdx.x - NCHUNK, tid, smem, X, wbf, perm, hb, el, er);
    }
}

// ---------------- FAT2: binB (blocks 0..199)  ||  gemm rows [50176, 100096) --------
__global__ __launch_bounds__(512, 4) void k_fat2(const unsigned int* __restrict__ binbuf,
        const int* __restrict__ cursor, int* __restrict__ cnt, int* __restrict__ bucket,
        const float* __restrict__ X, const unsigned short* __restrict__ wbf,
        const int* __restrict__ perm, unsigned short* __restrict__ hb,
        float* __restrict__ el, float* __restrict__ er) {
    __shared__ __align__(16) unsigned char smem[73728];
    if (blockIdx.x < NBIN) {
        int* cnt_l = (int*)smem;                      // 2000 B
        const int b = blockIdx.x;
        const int n = min(cursor[b], BINCAP);
        for (int i = threadIdx.x; i < BINW; i += 512) cnt_l[i] = 0;
        __syncthreads();
        const unsigned int* bp = binbuf + (long)b * BINCAP;
        for (int i = threadIdx.x; i < n; i += 512) {
            unsigned p = bp[i];
            int dl = (int)(p >> 17);
            int s  = (int)(p & 0x1FFFFu);
            int pos = atomicAdd(&cnt_l[dl], 1);
            if (pos < CAP) bucket[((long)b * BINW + dl) * CAP + pos] = s;
        }
        __syncthreads();
        for (int i = threadIdx.x; i < BINW; i += 512) cnt[b * BINW + i] = cnt_l[i];
    } else {
        gemm_role(GEMS1 + (blockIdx.x - NBIN), threadIdx.x, smem, X, wbf, perm,
                  hb, el, er);
    }
}

// ---------------- K4: aggregation (4 edge slots in flight), softmax, ELU ----------
// lane = g*16 + l4: g = edge slot (0..3), l4 = col chunk (8 cols, 16 B).
__global__ __launch_bounds__(256) void k_aggr(const float* __restrict__ el,
        const float* __restrict__ er, const int* __restrict__ cnt,
        const int* __restrict__ bucket, const unsigned short* __restrict__ hb,
        float* __restrict__ out) {
    int wid = (int)((blockIdx.x * (long)blockDim.x + threadIdx.x) >> 6);
    if (wid >= N_NODES) return;
    const int lane = threadIdx.x & 63;
    const int g    = lane >> 4;
    const int l4   = lane & 15;
    const int head = l4 >> 2;
    int deg = cnt[wid];
    if (deg > CAP) deg = CAP;
    const float ern = er[(long)wid * 4 + head];
    int myS = (lane < deg) ? bucket[(long)wid * CAP + lane] : 0;
    float acc[8];
#pragma unroll
    for (int j = 0; j < 8; j++) acc[j] = 0.f;
    float asum = 0.f;
    for (int i = 0; i < deg; i += 4) {
        int e = i + g;
        int s = __shfl(myS, e & 63, 64);
        u16x8 hv = *(const u16x8*)(hb + (long)s * HD + l4 * 8);
        float a = 0.f;
        if (e < deg) {
            float v = el[(long)s * 4 + head] + ern;
            v = v > 0.f ? v : NEG_SLOPE * v;
            a = __expf(v);
        }
        asum += a;
#pragma unroll
        for (int j = 0; j < 8; j++) acc[j] += bf2f(hv[j]) * a;
    }
#pragma unroll
    for (int off = 16; off <= 32; off <<= 1) {
        asum += __shfl_xor(asum, off, 64);
#pragma unroll
        for (int j = 0; j < 8; j++) acc[j] += __shfl_xor(acc[j], off, 64);
    }
    if (g == 0) {
        float inv = asum > 0.f ? 1.f / asum : 0.f;
        float4 o0, o1;
        float t;
        t = acc[0] * inv; o0.x = t > 0.f ? t : __expf(t) - 1.f;
        t = acc[1] * inv; o0.y = t > 0.f ? t : __expf(t) - 1.f;
        t = acc[2] * inv; o0.z = t > 0.f ? t : __expf(t) - 1.f;
        t = acc[3] * inv; o0.w = t > 0.f ? t : __expf(t) - 1.f;
        t = acc[4] * inv; o1.x = t > 0.f ? t : __expf(t) - 1.f;
        t = acc[5] * inv; o1.y = t > 0.f ? t : __expf(t) - 1.f;
        t = acc[6] * inv; o1.z = t > 0.f ? t : __expf(t) - 1.f;
        t = acc[7] * inv; o1.w = t > 0.f ? t : __expf(t) - 1.f;
        float* op = out + (long)wid * HD + l4 * 8;
        *(float4*)op = o0;
        *(float4*)(op + 4) = o1;
    }
}

// ---------------- launch ----------------
extern "C" void kernel_launch(void* const* d_in, const int* in_sizes, int n_in,
                              void* d_out, int out_size, void* d_ws, size_t ws_size,
                              hipStream_t stream) {
    const float* features = (const float*)d_in[0];
    const float* W        = (const float*)d_in[1];
    const float* attn_l   = (const float*)d_in[2];
    const float* attn_r   = (const float*)d_in[3];
    const int*   src      = (const int*)d_in[4];
    const int*   dst      = (const int*)d_in[5];
    const int*   perm     = (const int*)d_in[6];
    float* out = (float*)d_out;

    char* ws = (char*)d_ws;
    const size_t OFF_HB   = 0;                 // N*128 bf16 = 25,600,000 B
    const size_t OFF_EL   = 25600000;          // N*4 f32
    const size_t OFF_ER   = 27200000;
    const size_t OFF_CNT  = 28800000;          // N int
    const size_t OFF_CUR  = 29200000;          // NBIN ints (4 KB reserved)
    const size_t OFF_WBF  = 29204096;          // 144*512 = 73,728 B (reserve 81,920)
    const size_t OFF_BKT  = 29286016;          // N*CAP int = 25,600,000 B
    const size_t OFF_BINB = 54886016;          // NBIN*BINCAP u32 = 13,107,200 B
    // end ~68.0 MB

    unsigned short* hb    = (unsigned short*)(ws + OFF_HB);
    float* el     = (float*)(ws + OFF_EL);
    float* er     = (float*)(ws + OFF_ER);
    int*   cnt    = (int*)(ws + OFF_CNT);
    int*   cursor = (int*)(ws + OFF_CUR);
    unsigned short* wbf = (unsigned short*)(ws + OFF_WBF);
    int*   bucket = (int*)(ws + OFF_BKT);
    unsigned int* binbuf = (unsigned int*)(ws + OFF_BINB);

    k_prep<<<F_IN, NC, 0, stream>>>(W, attn_l, attn_r, wbf, cursor);
    k_fat1<<<NCHUNK + GEMS1, 512, 0, stream>>>(features, wbf, perm, hb, el, er,
                                               src, dst, cursor, binbuf);
    k_fat2<<<NBIN + GEMS2, 512, 0, stream>>>(binbuf, cursor, cnt, bucket,
                                             features, wbf, perm, hb, el, er);
    k_aggr<<<(N_NODES * 64 + 255) / 256, 256, 0, stream>>>(el, er, cnt, bucket, hb, out);
}

// Round 13
// 130.367 us; speedup vs baseline: 1.4307x; 1.0703x over previous
//
#include <hip/hip_runtime.h>
#include <hip/hip_bf16.h>
#include <math.h>

#define N_NODES 100000
#define E_EDGES 1600000
#define F_IN    256
#define HD      128     // H*D
#define NHEAD   4
#define DHEAD   32
#define NEG_SLOPE 0.2f
#define NBIN    200
#define BINW    500     // dsts per bin
#define CHUNK   8192
#define NCHUNK  196     // ceil(1.6M / 8192)
#define BINCAP  16384   // slots per bin (mean 8000)
#define NC      144     // gemm cols: 128 h + 4 el + 4 er + 8 pad
#define NCT     9       // col tiles of 16
#define GEMS1   196     // gemm blocks in fat1 (rows 0..50175, 256 rows/block)
#define GEMS2   195     // gemm blocks in fat2 (rows 50176..100095)

typedef __attribute__((ext_vector_type(8))) __bf16 bf16x8;
typedef __attribute__((ext_vector_type(4))) float  f32x4;
typedef __attribute__((ext_vector_type(8))) unsigned short u16x8;

__device__ __forceinline__ unsigned short f2bf(float x) {
    unsigned int b = __float_as_uint(x);
    b += 0x7fffu + ((b >> 16) & 1u);       // round-to-nearest-even
    return (unsigned short)(b >> 16);
}
__device__ __forceinline__ float bf2f(unsigned short u) {
    return __uint_as_float((unsigned int)u << 16);
}

// ---------------- K0: build 144-col bf16 weight buffer, pre-swizzled ----------------
// cols 0..127 = W; col 128+h = W @ attn_l[h]; col 132+h = W @ attn_r[h]; 136.. = 0.
// byte position = c*512 + ((2k) ^ ((c&7)<<4)). Block 0 also zeroes cursor.
__global__ void k_prep(const float* __restrict__ W, const float* __restrict__ al,
                       const float* __restrict__ ar, unsigned short* __restrict__ wbf,
                       int* __restrict__ cursor) {
    if (blockIdx.x == 0) {
        for (int i = threadIdx.x; i < NBIN; i += NC) cursor[i] = 0;
    }
    const int k = blockIdx.x;       // 0..255
    const int c = threadIdx.x;      // 0..143
    float v;
    if (c < 128) {
        v = W[k * HD + c];
    } else if (c < 132) {
        int h = c - 128; float s = 0.f;
        for (int d = 0; d < DHEAD; d++) s += W[k * HD + h * DHEAD + d] * al[h * DHEAD + d];
        v = s;
    } else if (c < 136) {
        int h = c - 132; float s = 0.f;
        for (int d = 0; d < DHEAD; d++) s += W[k * HD + h * DHEAD + d] * ar[h * DHEAD + d];
        v = s;
    } else {
        v = 0.f;
    }
    *(unsigned short*)((char*)wbf + (size_t)c * 512 + ((2 * k) ^ ((c & 7) << 4))) = f2bf(v);
}

// ---------------- shared gemm role: 512 thr, 256 rows/block, 144 cols ----------
__device__ __forceinline__ void gemm_role(int bid, int tid,
        unsigned char* smem, const float* __restrict__ X,
        const unsigned short* __restrict__ wbf, const int* __restrict__ perm,
        unsigned short* __restrict__ hb, float* __restrict__ el,
        float* __restrict__ er) {
    unsigned short* Bs = (unsigned short*)smem;   // NC*512 = 73728 B swizzled W'
    {   // linear stage (16B chunks): 4608 float4 / 512 thr = 9 each
        const float4* srcv = (const float4*)wbf;
        float4* dstv = (float4*)Bs;
#pragma unroll
        for (int i = 0; i < 9; i++) dstv[tid + i * 512] = srcv[tid + i * 512];
    }
    __syncthreads();

    const int l   = tid & 63;
    const int wv  = tid >> 6;           // 0..7
    const int l15 = l & 15;
    const int kg  = l >> 4;
    const int rowbase = bid * 256 + wv * 32;

    int r0 = rowbase + l15;      if (r0 >= N_NODES) r0 = N_NODES - 1;
    int r1 = rowbase + 16 + l15; if (r1 >= N_NODES) r1 = N_NODES - 1;
    const float* aptr0 = X + (long)perm[r0] * F_IN + kg * 8;
    const float* aptr1 = X + (long)perm[r1] * F_IN + kg * 8;

    f32x4 acc[2][NCT];
#pragma unroll
    for (int rt = 0; rt < 2; rt++)
#pragma unroll
        for (int ct = 0; ct < NCT; ct++) acc[rt][ct] = (f32x4){0.f, 0.f, 0.f, 0.f};

#pragma unroll
    for (int k0 = 0; k0 < F_IN; k0 += 32) {
        bf16x8 a0, a1;
        {
            float4 v0 = *(const float4*)(aptr0 + k0);
            float4 v1 = *(const float4*)(aptr0 + k0 + 4);
            a0[0]=(__bf16)v0.x; a0[1]=(__bf16)v0.y; a0[2]=(__bf16)v0.z; a0[3]=(__bf16)v0.w;
            a0[4]=(__bf16)v1.x; a0[5]=(__bf16)v1.y; a0[6]=(__bf16)v1.z; a0[7]=(__bf16)v1.w;
        }
        {
            float4 v0 = *(const float4*)(aptr1 + k0);
            float4 v1 = *(const float4*)(aptr1 + k0 + 4);
            a1[0]=(__bf16)v0.x; a1[1]=(__bf16)v0.y; a1[2]=(__bf16)v0.z; a1[3]=(__bf16)v0.w;
            a1[4]=(__bf16)v1.x; a1[5]=(__bf16)v1.y; a1[6]=(__bf16)v1.z; a1[7]=(__bf16)v1.w;
        }
        const int sb = k0 * 2 + kg * 16;
#pragma unroll
        for (int ct = 0; ct < NCT; ct++) {
            int c = ct * 16 + l15;
            bf16x8 b = *(const bf16x8*)((const char*)Bs + c * 512 + (sb ^ ((c & 7) << 4)));
            acc[0][ct] = __builtin_amdgcn_mfma_f32_16x16x32_bf16(a0, b, acc[0][ct], 0, 0, 0);
            acc[1][ct] = __builtin_amdgcn_mfma_f32_16x16x32_bf16(a1, b, acc[1][ct], 0, 0, 0);
        }
    }

    // C/D layout: col = l&15, row = (l>>4)*4 + reg (m89-verified)
#pragma unroll
    for (int rt = 0; rt < 2; rt++)
#pragma unroll
        for (int i = 0; i < 4; i++) {
            int row = rowbase + rt * 16 + kg * 4 + i;
            if (row < N_NODES) {
                unsigned short* op = hb + (long)row * HD + l15;
#pragma unroll
                for (int ct = 0; ct < 8; ct++) op[ct * 16] = f2bf(acc[rt][ct][i]);
                float v = acc[rt][8][i];
                if (l15 < 4)      el[(long)row * 4 + l15]       = v;
                else if (l15 < 8) er[(long)row * 4 + (l15 - 4)] = v;
            }
        }
}

// ---------------- FAT1: binA (blocks 0..195)  ||  gemm rows [0, 50176) ----------
__global__ __launch_bounds__(512, 4) void k_fat1(const float* __restrict__ X,
        const unsigned short* __restrict__ wbf, const int* __restrict__ perm,
        unsigned short* __restrict__ hb, float* __restrict__ el, float* __restrict__ er,
        const int* __restrict__ src, const int* __restrict__ dst,
        int* __restrict__ cursor, unsigned int* __restrict__ binbuf) {
    __shared__ __align__(16) unsigned char smem[73728];
    const int tid = threadIdx.x;

    if (blockIdx.x < NCHUNK) {
        // ---------------- binA role ----------------
        unsigned int*  buf     = (unsigned int*)smem;             // 32768 B
        unsigned char* binid   = smem + 32768;                    //  8192 B
        unsigned int*  hist    = (unsigned int*)(smem + 40960);
        unsigned int*  pfx     = (unsigned int*)(smem + 41792);
        unsigned int*  base_sh = (unsigned int*)(smem + 42624);
        unsigned int*  cnt2    = (unsigned int*)(smem + 43456);
        const int e0 = blockIdx.x * CHUNK;
        const int n = min(CHUNK, E_EDGES - e0);

        for (int i = tid; i < NBIN; i += 512) { hist[i] = 0; cnt2[i] = 0; }
        __syncthreads();
        for (int i = tid; i < n; i += 512) {
            int d = dst[e0 + i];
            atomicAdd(&hist[d / BINW], 1u);
        }
        __syncthreads();
        if (tid < NBIN) pfx[tid] = hist[tid];
        __syncthreads();
        for (int off = 1; off < NBIN; off <<= 1) {     // inclusive scan
            unsigned v = (tid < NBIN) ? pfx[tid] : 0;
            unsigned u = (tid >= off && tid < NBIN) ? pfx[tid - off] : 0;
            __syncthreads();
            if (tid < NBIN) pfx[tid] = v + u;
            __syncthreads();
        }
        if (tid < NBIN) base_sh[tid] = (unsigned)atomicAdd(cursor + tid, (int)hist[tid]);
        __syncthreads();
        for (int i = tid; i < n; i += 512) {
            int d = dst[e0 + i];
            int s = src[e0 + i];
            int b = d / BINW;
            unsigned pos = atomicAdd(&cnt2[b], 1u);
            unsigned idx = pfx[b] - hist[b] + pos;
            buf[idx] = ((unsigned)(d - b * BINW) << 17) | (unsigned)s;
            binid[idx] = (unsigned char)b;
        }
        __syncthreads();
        for (int i = tid; i < n; i += 512) {
            int b = binid[i];
            unsigned ex = pfx[b] - hist[b];
            unsigned gpos = base_sh[b] + ((unsigned)i - ex);
            if (gpos < BINCAP) binbuf[(long)b * BINCAP + gpos] = buf[i];
        }
    } else {
        gemm_role(blockIdx.x - NCHUNK, tid, smem, X, wbf, perm, hb, el, er);
    }
}

// ---------------- FAT2: binB/CSR (blocks 0..199)  ||  gemm rows [50176, 100096) ----
// binB role: counting-sort the bin's entries into a PACKED global CSR:
// base[gd], cnt[gd]; csr rows contiguous -> k_aggr fetches ~payload bytes only.
__global__ __launch_bounds__(512, 4) void k_fat2(const unsigned int* __restrict__ binbuf,
        const int* __restrict__ cursor, int* __restrict__ cnt, int* __restrict__ basearr,
        int* __restrict__ csr,
        const float* __restrict__ X, const unsigned short* __restrict__ wbf,
        const int* __restrict__ perm, unsigned short* __restrict__ hb,
        float* __restrict__ el, float* __restrict__ er) {
    __shared__ __align__(16) unsigned char smem[73728];
    const int tid = threadIdx.x;
    if (blockIdx.x < NBIN) {
        int* cnt_l = (int*)smem;                  // 500 ints
        int* pfx_l = (int*)(smem + 2048);         // 500 ints
        int* pos_l = (int*)(smem + 4096);         // 500 ints
        int* redsh = (int*)(smem + 6144);         // 8 + 1 ints
        const int b = blockIdx.x;
        const int n = min(cursor[b], BINCAP);

        // binbase = sum_{i<b} min(cursor[i], BINCAP)
        int part = (tid < b) ? min(cursor[tid], BINCAP) : 0;
#pragma unroll
        for (int off = 32; off; off >>= 1) part += __shfl_xor(part, off, 64);
        if ((tid & 63) == 0) redsh[tid >> 6] = part;
        for (int i = tid; i < BINW; i += 512) { cnt_l[i] = 0; pos_l[i] = 0; }
        __syncthreads();
        if (tid == 0) {
            int s = 0;
            for (int i = 0; i < 8; i++) s += redsh[i];
            redsh[8] = s;
        }
        __syncthreads();
        const int binbase = redsh[8];

        const unsigned int* bp = binbuf + (long)b * BINCAP;
        for (int i = tid; i < n; i += 512) atomicAdd(&cnt_l[bp[i] >> 17], 1);
        __syncthreads();
        if (tid < BINW) pfx_l[tid] = cnt_l[tid];
        __syncthreads();
        for (int off = 1; off < BINW; off <<= 1) {     // inclusive scan over 500
            int v = (tid < BINW) ? pfx_l[tid] : 0;
            int u = (tid >= off && tid < BINW) ? pfx_l[tid - off] : 0;
            __syncthreads();
            if (tid < BINW) pfx_l[tid] = v + u;
            __syncthreads();
        }
        // exclusive base per dst = pfx_l[dl] - cnt_l[dl]
        for (int i = tid; i < n; i += 512) {
            unsigned p = bp[i];
            int dl = (int)(p >> 17);
            int s  = (int)(p & 0x1FFFFu);
            int pos = atomicAdd(&pos_l[dl], 1);
            csr[binbase + (pfx_l[dl] - cnt_l[dl]) + pos] = s;
        }
        __syncthreads();
        for (int i = tid; i < BINW; i += 512) {
            int gd = b * BINW + i;
            cnt[gd]     = cnt_l[i];
            basearr[gd] = binbase + pfx_l[i] - cnt_l[i];
        }
    } else {
        gemm_role(GEMS1 + (blockIdx.x - NBIN), tid, smem, X, wbf, perm, hb, el, er);
    }
}

// ---------------- K4: aggregation (4 edge slots in flight), packed CSR ----------
// lane = g*16 + l4: g = edge slot (0..3), l4 = col chunk (8 cols, 16 B).
__global__ __launch_bounds__(256) void k_aggr(const float* __restrict__ el,
        const float* __restrict__ er, const int* __restrict__ cnt,
        const int* __restrict__ basearr, const int* __restrict__ csr,
        const unsigned short* __restrict__ hb, float* __restrict__ out) {
    int wid = (int)((blockIdx.x * (long)blockDim.x + threadIdx.x) >> 6);
    if (wid >= N_NODES) return;
    const int lane = threadIdx.x & 63;
    const int g    = lane >> 4;
    const int l4   = lane & 15;
    const int head = l4 >> 2;
    int deg = cnt[wid];
    if (deg > 64) deg = 64;
    const int base = basearr[wid];
    const float ern = er[(long)wid * 4 + head];
    int myS = (lane < deg) ? csr[base + lane] : 0;
    float acc[8];
#pragma unroll
    for (int j = 0; j < 8; j++) acc[j] = 0.f;
    float asum = 0.f;
    for (int i = 0; i < deg; i += 4) {
        int e = i + g;
        int s = __shfl(myS, e & 63, 64);
        u16x8 hv = *(const u16x8*)(hb + (long)s * HD + l4 * 8);
        float a = 0.f;
        if (e < deg) {
            float v = el[(long)s * 4 + head] + ern;
            v = v > 0.f ? v : NEG_SLOPE * v;
            a = __expf(v);
        }
        asum += a;
#pragma unroll
        for (int j = 0; j < 8; j++) acc[j] += bf2f(hv[j]) * a;
    }
#pragma unroll
    for (int off = 16; off <= 32; off <<= 1) {
        asum += __shfl_xor(asum, off, 64);
#pragma unroll
        for (int j = 0; j < 8; j++) acc[j] += __shfl_xor(acc[j], off, 64);
    }
    if (g == 0) {
        float inv = asum > 0.f ? 1.f / asum : 0.f;
        float4 o0, o1;
        float t;
        t = acc[0] * inv; o0.x = t > 0.f ? t : __expf(t) - 1.f;
        t = acc[1] * inv; o0.y = t > 0.f ? t : __expf(t) - 1.f;
        t = acc[2] * inv; o0.z = t > 0.f ? t : __expf(t) - 1.f;
        t = acc[3] * inv; o0.w = t > 0.f ? t : __expf(t) - 1.f;
        t = acc[4] * inv; o1.x = t > 0.f ? t : __expf(t) - 1.f;
        t = acc[5] * inv; o1.y = t > 0.f ? t : __expf(t) - 1.f;
        t = acc[6] * inv; o1.z = t > 0.f ? t : __expf(t) - 1.f;
        t = acc[7] * inv; o1.w = t > 0.f ? t : __expf(t) - 1.f;
        float* op = out + (long)wid * HD + l4 * 8;
        *(float4*)op = o0;
        *(float4*)(op + 4) = o1;
    }
}

// ---------------- launch ----------------
extern "C" void kernel_launch(void* const* d_in, const int* in_sizes, int n_in,
                              void* d_out, int out_size, void* d_ws, size_t ws_size,
                              hipStream_t stream) {
    const float* features = (const float*)d_in[0];
    const float* W        = (const float*)d_in[1];
    const float* attn_l   = (const float*)d_in[2];
    const float* attn_r   = (const float*)d_in[3];
    const int*   src      = (const int*)d_in[4];
    const int*   dst      = (const int*)d_in[5];
    const int*   perm     = (const int*)d_in[6];
    float* out = (float*)d_out;

    char* ws = (char*)d_ws;
    const size_t OFF_HB   = 0;                 // N*128 bf16 = 25,600,000 B
    const size_t OFF_EL   = 25600000;          // N*4 f32
    const size_t OFF_ER   = 27200000;
    const size_t OFF_CNT  = 28800000;          // N int
    const size_t OFF_BASE = 29200000;          // N int
    const size_t OFF_CUR  = 29600000;          // NBIN ints (4 KB reserved)
    const size_t OFF_WBF  = 29604096;          // 144*512 = 73,728 B (reserve 81,920)
    const size_t OFF_CSR  = 29686016;          // E ints = 6,400,000 B
    const size_t OFF_BINB = 36086016;          // NBIN*BINCAP u32 = 13,107,200 B
    // end ~49.2 MB

    unsigned short* hb    = (unsigned short*)(ws + OFF_HB);
    float* el     = (float*)(ws + OFF_EL);
    float* er     = (float*)(ws + OFF_ER);
    int*   cnt    = (int*)(ws + OFF_CNT);
    int*   basearr= (int*)(ws + OFF_BASE);
    int*   cursor = (int*)(ws + OFF_CUR);
    unsigned short* wbf = (unsigned short*)(ws + OFF_WBF);
    int*   csr    = (int*)(ws + OFF_CSR);
    unsigned int* binbuf = (unsigned int*)(ws + OFF_BINB);

    k_prep<<<F_IN, NC, 0, stream>>>(W, attn_l, attn_r, wbf, cursor);
    k_fat1<<<NCHUNK + GEMS1, 512, 0, stream>>>(features, wbf, perm, hb, el, er,
                                               src, dst, cursor, binbuf);
    k_fat2<<<NBIN + GEMS2, 512, 0, stream>>>(binbuf, cursor, cnt, basearr, csr,
                                             features, wbf, perm, hb, el, er);
    k_aggr<<<(N_NODES * 64 + 255) / 256, 256, 0, stream>>>(el, er, cnt, basearr, csr,
                                                           hb, out);
}